// Round 2
// baseline (824.589 us; speedup 1.0000x reference)
//
#include <hip/hip_runtime.h>
#include <cstdint>
#include <cstddef>

#define D 64
#define CAP 3072
#define OCAP 8192

// ---------------- build compact slot maps ----------------
__global__ __launch_bounds__(256) void k_build_maps(const int* __restrict__ user_id,
                                                    const int* __restrict__ item_id,
                                                    int* __restrict__ map_u,
                                                    int* __restrict__ map_i, int B)
{
    int i = blockIdx.x * blockDim.x + threadIdx.x;
    if (i < B) {
        atomicCAS(&map_u[user_id[i]], -1, i);
        atomicCAS(&map_i[item_id[i]], -1, i);
    }
}

// ---------------- phase C: bin hit edges by slot bucket ----------------
// bucket = slot>>5 (32 slots per bucket). Entry packs (slot&31)<<17 | src_row.
__global__ __launch_bounds__(256) void k_bin(const int* __restrict__ edge_user,
                                             const int* __restrict__ edge_item,
                                             const int* __restrict__ map_u,
                                             const int* __restrict__ map_i,
                                             int* __restrict__ cnt,          // [1024]
                                             uint32_t* __restrict__ binU,
                                             uint32_t* __restrict__ binI,
                                             int* __restrict__ ovfCnt,
                                             uint32_t* __restrict__ ovf, int E)
{
    int e = blockIdx.x * blockDim.x + threadIdx.x;
    if (e >= E) return;
    int u = edge_user[e], it = edge_item[e];
    int su = map_u[u];
    int si = map_i[it];
    if (su >= 0) {
        int pos = atomicAdd(&cnt[su >> 5], 1);
        if (pos < CAP)
            binU[(size_t)(su >> 5) * CAP + pos] = ((uint32_t)(su & 31) << 17) | (uint32_t)it;
        else {
            int o = atomicAdd(ovfCnt, 1);
            if (o < OCAP) ovf[o] = ((uint32_t)su << 17) | (uint32_t)it;
        }
    }
    if (si >= 0) {
        int pos = atomicAdd(&cnt[512 + (si >> 5)], 1);
        if (pos < CAP)
            binI[(size_t)(si >> 5) * CAP + pos] = ((uint32_t)(si & 31) << 17) | (uint32_t)u;
        else {
            int o = atomicAdd(ovfCnt, 1);
            if (o < OCAP) ovf[o] = 0x80000000u | ((uint32_t)si << 17) | (uint32_t)u;
        }
    }
}

// ---------------- phase D: per-bucket LDS accumulation ----------------
// block b<512: user-side bucket b (gathers item rows). b>=512: item-side.
__global__ __launch_bounds__(256) void k_reduce(const uint32_t* __restrict__ binU,
                                                const uint32_t* __restrict__ binI,
                                                const int* __restrict__ cnt,
                                                const float* __restrict__ user_table,
                                                const float* __restrict__ item_table,
                                                float* __restrict__ aggIU,
                                                float* __restrict__ aggUI,
                                                int* __restrict__ degU,
                                                int* __restrict__ degI)
{
    __shared__ float acc[32][64];
    __shared__ int dcnt[32];
    int tid = threadIdx.x;
    {
        float4 z = {0.f, 0.f, 0.f, 0.f};
        float4* a4 = (float4*)&acc[0][0];
        a4[tid] = z;
        a4[tid + 256] = z;
        if (tid < 32) dcnt[tid] = 0;
    }
    __syncthreads();

    int b = blockIdx.x;
    int side = b >> 9;
    int bb = b & 511;
    int n = cnt[b];
    if (n > CAP) n = CAP;
    const uint32_t* bin = (side ? binI : binU) + (size_t)bb * CAP;
    const float* table = side ? user_table : item_table;

    int lane = tid & 63, w = tid >> 6;
    int g = lane >> 4, l16 = lane & 15;
    // 4 waves x 4 sixteen-lane groups: 16 entries in flight per block iteration
    for (int i0 = w * 4; i0 < n; i0 += 16) {
        int i = i0 + g;
        if (i < n) {
            uint32_t p = bin[i];
            int slot = p >> 17;
            int row = (int)(p & 0x1FFFFu);
            float4 v = ((const float4*)table)[(size_t)row * 16 + l16];
            int c = l16 * 4;
            atomicAdd(&acc[slot][c + 0], v.x);
            atomicAdd(&acc[slot][c + 1], v.y);
            atomicAdd(&acc[slot][c + 2], v.z);
            atomicAdd(&acc[slot][c + 3], v.w);
            if (l16 == 0) atomicAdd(&dcnt[slot], 1);
        }
    }
    __syncthreads();

    float* aggOut = side ? aggUI : aggIU;
    int* degOut = side ? degI : degU;
    int slotBase = bb * 32;
    float4* accF4 = (float4*)&acc[0][0];
    float4* outF4 = (float4*)(aggOut + (size_t)slotBase * 64);
    outF4[tid] = accF4[tid];
    outF4[tid + 256] = accF4[tid + 256];
    if (tid < 32) degOut[slotBase + tid] = dcnt[tid];
}

// ---------------- overflow drain (expected n==0) ----------------
__global__ __launch_bounds__(256) void k_ovf(const int* __restrict__ ovfCnt,
                                             const uint32_t* __restrict__ ovf,
                                             const float* __restrict__ user_table,
                                             const float* __restrict__ item_table,
                                             float* __restrict__ aggIU,
                                             float* __restrict__ aggUI,
                                             int* __restrict__ degU,
                                             int* __restrict__ degI)
{
    int n = *ovfCnt;
    if (n > OCAP) n = OCAP;
    int wid = (blockIdx.x * blockDim.x + threadIdx.x) >> 6;
    int lane = threadIdx.x & 63;
    int nw = (gridDim.x * blockDim.x) >> 6;
    for (int j = wid; j < n; j += nw) {
        uint32_t p = ovf[j];
        int side = p >> 31;
        int slot = (int)((p >> 17) & 0x3FFFu);
        int row = (int)(p & 0x1FFFFu);
        const float* t = side ? user_table : item_table;
        float v = t[(size_t)row * D + lane];
        float* agg = side ? aggUI : aggIU;
        atomicAdd(&agg[(size_t)slot * D + lane], v);
        if (lane == 0) atomicAdd(&(side ? degI : degU)[slot], 1);
    }
}

// ---------------- per-row GCN transform + feature build ----------------
__global__ __launch_bounds__(256) void k_build_x(const int* __restrict__ user_id,
                                                 const int* __restrict__ item_id,
                                                 const int* __restrict__ map_u,
                                                 const int* __restrict__ map_i,
                                                 const int* __restrict__ degU,
                                                 const int* __restrict__ degI,
                                                 const float* __restrict__ aggIU,
                                                 const float* __restrict__ aggUI,
                                                 const float* __restrict__ user_table,
                                                 const float* __restrict__ item_table,
                                                 const float* __restrict__ Wu,
                                                 const float* __restrict__ bu,
                                                 const float* __restrict__ Wi,
                                                 const float* __restrict__ bi,
                                                 float* __restrict__ x, int B)
{
    __shared__ float WuL[D * D];
    __shared__ float WiL[D * D];
    for (int t = threadIdx.x; t < D * D; t += blockDim.x) {
        WuL[t] = Wu[t];
        WiL[t] = Wi[t];
    }
    __syncthreads();

    int wid = (blockIdx.x * blockDim.x + threadIdx.x) >> 6;
    int lane = threadIdx.x & 63;
    if (wid >= B) return;

    int u  = user_id[wid];
    int it = item_id[wid];
    int su = map_u[u];
    int si = map_i[it];
    float du = (float)degU[su] + 1.0f;
    float di = (float)degI[si] + 1.0f;
    float gih = aggIU[(size_t)su * D + lane] / du;  // gcn_item_h[lane]
    float guh = aggUI[(size_t)si * D + lane] / di;  // gcn_user_h[lane]

    float accU = bu[lane];
    float accI = bi[lane];
    #pragma unroll 8
    for (int k = 0; k < D; ++k) {
        float gk = __shfl(guh, k);
        accU = fmaf(gk, WuL[k * D + lane], accU);
        float hk = __shfl(gih, k);
        accI = fmaf(hk, WiL[k * D + lane], accI);
    }
    float guo = fmaxf(accU, 0.0f);
    float gio = fmaxf(accI, 0.0f);
    float ue = user_table[(size_t)u * D + lane];
    float ie = item_table[(size_t)it * D + lane];

    size_t xb = (size_t)wid * 256;
    x[xb + lane]       = ue * ie;
    x[xb + 64 + lane]  = ue * gio;
    x[xb + 128 + lane] = guo * ie;
    x[xb + 192 + lane] = guo * gio;
}

// ---------------- layer 1: [B,256]@[256,128] + b1, tanh ----------------
__global__ __launch_bounds__(256) void k_gemm1(const float* __restrict__ x,
                                               const float* __restrict__ W1,
                                               const float* __restrict__ b1,
                                               float* __restrict__ x1, int B)
{
    __shared__ float xs[32][65];
    __shared__ float ws[32][128];
    int tid = threadIdx.x;
    int tx = tid & 31;
    int ty = tid >> 5;
    int row0 = blockIdx.x * 64;
    float acc[8][4] = {};

    for (int k0 = 0; k0 < 256; k0 += 32) {
        {
            int r = tid >> 2;
            int kk = (tid & 3) * 8;
            const float4* src = (const float4*)&x[(size_t)(row0 + r) * 256 + k0 + kk];
            float4 v0 = src[0], v1 = src[1];
            xs[kk + 0][r] = v0.x; xs[kk + 1][r] = v0.y; xs[kk + 2][r] = v0.z; xs[kk + 3][r] = v0.w;
            xs[kk + 4][r] = v1.x; xs[kk + 5][r] = v1.y; xs[kk + 6][r] = v1.z; xs[kk + 7][r] = v1.w;
        }
        {
            const float4* src = (const float4*)(W1 + (size_t)k0 * 128);
            float4* dst = (float4*)&ws[0][0];
            #pragma unroll
            for (int q = 0; q < 4; ++q) dst[tid + q * 256] = src[tid + q * 256];
        }
        __syncthreads();
        #pragma unroll
        for (int k = 0; k < 32; ++k) {
            float a[8], b[4];
            #pragma unroll
            for (int r = 0; r < 8; ++r) a[r] = xs[k][ty * 8 + r];
            #pragma unroll
            for (int c = 0; c < 4; ++c) b[c] = ws[k][tx + 32 * c];
            #pragma unroll
            for (int r = 0; r < 8; ++r)
                #pragma unroll
                for (int c = 0; c < 4; ++c)
                    acc[r][c] = fmaf(a[r], b[c], acc[r][c]);
        }
        __syncthreads();
    }
    #pragma unroll
    for (int r = 0; r < 8; ++r) {
        int row = row0 + ty * 8 + r;
        #pragma unroll
        for (int c = 0; c < 4; ++c) {
            int col = tx + 32 * c;
            x1[(size_t)row * 128 + col] = tanhf(acc[r][c] + b1[col]);
        }
    }
}

// ---------------- layer 2: [B,128]@[128,64] + b2, tanh ----------------
__global__ __launch_bounds__(256) void k_gemm2(const float* __restrict__ x1,
                                               const float* __restrict__ W2,
                                               const float* __restrict__ b2,
                                               float* __restrict__ x2, int B)
{
    __shared__ float xs[32][65];
    __shared__ float ws[32][64];
    int tid = threadIdx.x;
    int tx = tid & 15;
    int ty = tid >> 4;
    int row0 = blockIdx.x * 64;
    float acc[4][4] = {};

    for (int k0 = 0; k0 < 128; k0 += 32) {
        {
            int r = tid >> 2;
            int kk = (tid & 3) * 8;
            const float4* src = (const float4*)&x1[(size_t)(row0 + r) * 128 + k0 + kk];
            float4 v0 = src[0], v1 = src[1];
            xs[kk + 0][r] = v0.x; xs[kk + 1][r] = v0.y; xs[kk + 2][r] = v0.z; xs[kk + 3][r] = v0.w;
            xs[kk + 4][r] = v1.x; xs[kk + 5][r] = v1.y; xs[kk + 6][r] = v1.z; xs[kk + 7][r] = v1.w;
        }
        {
            const float4* src = (const float4*)(W2 + (size_t)k0 * 64);
            float4* dst = (float4*)&ws[0][0];
            #pragma unroll
            for (int q = 0; q < 2; ++q) dst[tid + q * 256] = src[tid + q * 256];
        }
        __syncthreads();
        #pragma unroll
        for (int k = 0; k < 32; ++k) {
            float a[4], b[4];
            #pragma unroll
            for (int r = 0; r < 4; ++r) a[r] = xs[k][ty * 4 + r];
            #pragma unroll
            for (int c = 0; c < 4; ++c) b[c] = ws[k][tx + 16 * c];
            #pragma unroll
            for (int r = 0; r < 4; ++r)
                #pragma unroll
                for (int c = 0; c < 4; ++c)
                    acc[r][c] = fmaf(a[r], b[c], acc[r][c]);
        }
        __syncthreads();
    }
    #pragma unroll
    for (int r = 0; r < 4; ++r) {
        int row = row0 + ty * 4 + r;
        #pragma unroll
        for (int c = 0; c < 4; ++c) {
            int col = tx + 16 * c;
            x2[(size_t)row * 64 + col] = tanhf(acc[r][c] + b2[col]);
        }
    }
}

// ---------------- final: dot with W3 + biases ----------------
__global__ __launch_bounds__(256) void k_final(const float* __restrict__ x2,
                                               const float* __restrict__ W3,
                                               const float* __restrict__ b3,
                                               const float* __restrict__ user_bias,
                                               const float* __restrict__ item_bias,
                                               const int* __restrict__ user_id,
                                               const int* __restrict__ item_id,
                                               float* __restrict__ out, int B)
{
    int wid = (blockIdx.x * blockDim.x + threadIdx.x) >> 6;
    int lane = threadIdx.x & 63;
    if (wid >= B) return;
    float v = x2[(size_t)wid * 64 + lane] * W3[lane];
    #pragma unroll
    for (int off = 32; off; off >>= 1) v += __shfl_xor(v, off);
    if (lane == 0)
        out[wid] = v + b3[0] + user_bias[user_id[wid]] + item_bias[item_id[wid]];
}

extern "C" void kernel_launch(void* const* d_in, const int* in_sizes, int n_in,
                              void* d_out, int out_size, void* d_ws, size_t ws_size,
                              hipStream_t stream)
{
    const float* user_table = (const float*)d_in[0];
    const float* item_table = (const float*)d_in[1];
    const float* Wu = (const float*)d_in[2];
    const float* bu = (const float*)d_in[3];
    const float* Wi = (const float*)d_in[4];
    const float* bi = (const float*)d_in[5];
    const float* W1 = (const float*)d_in[6];
    const float* b1 = (const float*)d_in[7];
    const float* W2 = (const float*)d_in[8];
    const float* b2 = (const float*)d_in[9];
    const float* W3 = (const float*)d_in[10];
    const float* b3 = (const float*)d_in[11];
    const float* user_bias = (const float*)d_in[12];
    const float* item_bias = (const float*)d_in[13];
    const int* user_id = (const int*)d_in[14];
    const int* item_id = (const int*)d_in[15];
    const int* edge_user = (const int*)d_in[16];
    const int* edge_item = (const int*)d_in[17];

    const int N_USER = in_sizes[0] / D;
    const int N_ITEM = in_sizes[1] / D;
    const int B = in_sizes[14];
    const int E = in_sizes[16];

    // ---- workspace layout (bytes) ----
    char* ws = (char*)d_ws;
    const size_t aggIU_off = 0;
    const size_t aggUI_off = aggIU_off + (size_t)B * D * 4;        // 4 MB
    const size_t degU_off  = aggUI_off + (size_t)B * D * 4;        // 8 MB
    const size_t degI_off  = degU_off + (size_t)B * 4;
    const size_t mapu_off  = degI_off + (size_t)B * 4;
    const size_t mapi_off  = mapu_off + (size_t)N_USER * 4;
    const size_t cnt_off   = mapi_off + (size_t)N_ITEM * 4;        // 1024 cnt + 1 ovfCnt
    size_t x_off = cnt_off + 1025 * 4;
    x_off = (x_off + 255) & ~(size_t)255;
    const size_t x1_off = x_off + (size_t)B * 256 * 4;             // x is 16 MB
    const size_t x2_off = x1_off + (size_t)B * 128 * 4;
    const size_t ovf_off = x2_off + (size_t)B * D * 4;

    float* aggIU = (float*)(ws + aggIU_off);
    float* aggUI = (float*)(ws + aggUI_off);
    int*   degU  = (int*)(ws + degU_off);
    int*   degI  = (int*)(ws + degI_off);
    int*   map_u = (int*)(ws + mapu_off);
    int*   map_i = (int*)(ws + mapi_off);
    int*   cnt   = (int*)(ws + cnt_off);
    int*   ovfCnt = cnt + 1024;
    float* x  = (float*)(ws + x_off);
    // bins overlay the x buffer (dead before k_build_x writes x)
    uint32_t* binU = (uint32_t*)(ws + x_off);                      // 512*CAP*4 = 6.3 MB
    uint32_t* binI = binU + (size_t)512 * CAP;                     // 6.3 MB more (x is 16.8 MB)
    float* x1 = (float*)(ws + x1_off);
    float* x2 = (float*)(ws + x2_off);
    uint32_t* ovf = (uint32_t*)(ws + ovf_off);

    hipMemsetAsync(ws + mapu_off, 0xFF, (size_t)(N_USER + N_ITEM) * 4, stream); // maps = -1
    hipMemsetAsync(ws + cnt_off, 0, 1025 * 4, stream);                          // cnt + ovfCnt = 0

    k_build_maps<<<(B + 255) / 256, 256, 0, stream>>>(user_id, item_id, map_u, map_i, B);

    k_bin<<<(E + 255) / 256, 256, 0, stream>>>(edge_user, edge_item, map_u, map_i,
                                               cnt, binU, binI, ovfCnt, ovf, E);

    k_reduce<<<1024, 256, 0, stream>>>(binU, binI, cnt, user_table, item_table,
                                       aggIU, aggUI, degU, degI);

    k_ovf<<<8, 256, 0, stream>>>(ovfCnt, ovf, user_table, item_table,
                                 aggIU, aggUI, degU, degI);

    k_build_x<<<B / 4, 256, 0, stream>>>(user_id, item_id, map_u, map_i, degU, degI,
                                         aggIU, aggUI, user_table, item_table,
                                         Wu, bu, Wi, bi, x, B);

    k_gemm1<<<B / 64, 256, 0, stream>>>(x, W1, b1, x1, B);
    k_gemm2<<<B / 64, 256, 0, stream>>>(x1, W2, b2, x2, B);

    k_final<<<B / 4, 256, 0, stream>>>(x2, W3, b3, user_bias, item_bias,
                                       user_id, item_id, (float*)d_out, B);
}

// Round 3
// 312.553 us; speedup vs baseline: 2.6382x; 2.6382x over previous
//
#include <hip/hip_runtime.h>
#include <cstdint>
#include <cstddef>

#define D 64
#define CAPU 96
#define CAPI 128
#define OCAP 4096

// ---------------- build compact slot maps ----------------
__global__ __launch_bounds__(256) void k_build_maps(const int* __restrict__ user_id,
                                                    const int* __restrict__ item_id,
                                                    int* __restrict__ map_u,
                                                    int* __restrict__ map_i, int B)
{
    int i = blockIdx.x * blockDim.x + threadIdx.x;
    if (i < B) {
        atomicCAS(&map_u[user_id[i]], -1, i);
        atomicCAS(&map_i[item_id[i]], -1, i);
    }
}

// ---------------- scatter hit edges into per-slot CSR lists ----------------
// counters padded to 64B (16 ints) so atomic RMWs never pile onto few lines.
__global__ __launch_bounds__(256) void k_scatter(const int* __restrict__ edge_user,
                                                 const int* __restrict__ edge_item,
                                                 const int* __restrict__ map_u,
                                                 const int* __restrict__ map_i,
                                                 int* __restrict__ cntU,
                                                 int* __restrict__ cntI,
                                                 uint32_t* __restrict__ listU,
                                                 uint32_t* __restrict__ listI,
                                                 int* __restrict__ ovfCnt,
                                                 uint32_t* __restrict__ ovf, int E)
{
    int e = blockIdx.x * blockDim.x + threadIdx.x;
    if (e >= E) return;
    int u = edge_user[e], it = edge_item[e];
    int su = map_u[u];
    int si = map_i[it];
    if (su >= 0) {
        int pos = atomicAdd(&cntU[su * 16], 1);
        if (pos < CAPU) listU[(size_t)su * CAPU + pos] = (uint32_t)it;
        else { int o = atomicAdd(ovfCnt, 1);
               if (o < OCAP) ovf[o] = ((uint32_t)su << 17) | (uint32_t)it; }
    }
    if (si >= 0) {
        int pos = atomicAdd(&cntI[si * 16], 1);
        if (pos < CAPI) listI[(size_t)si * CAPI + pos] = (uint32_t)u;
        else { int o = atomicAdd(ovfCnt, 1);
               if (o < OCAP) ovf[o] = 0x80000000u | ((uint32_t)si << 17) | (uint32_t)u; }
    }
}

// ---------------- gather-reduce: one wave per (side, slot) ----------------
__global__ __launch_bounds__(256) void k_gather(const uint32_t* __restrict__ listU,
                                                const uint32_t* __restrict__ listI,
                                                const int* __restrict__ cntU,
                                                const int* __restrict__ cntI,
                                                const float* __restrict__ user_table,
                                                const float* __restrict__ item_table,
                                                const int* __restrict__ ovfCnt,
                                                const uint32_t* __restrict__ ovf,
                                                float* __restrict__ aggIU,
                                                float* __restrict__ aggUI,
                                                int* __restrict__ degU,
                                                int* __restrict__ degI, int B)
{
    int gwid = (blockIdx.x * blockDim.x + threadIdx.x) >> 6;
    if (gwid >= 2 * B) return;
    int lane = threadIdx.x & 63;
    int side = gwid >= B;
    int slot = side ? gwid - B : gwid;
    int cnt = side ? cntI[slot * 16] : cntU[slot * 16];
    int caps = side ? CAPI : CAPU;
    int n = cnt < caps ? cnt : caps;
    const uint32_t* list = side ? (listI + (size_t)slot * CAPI)
                                : (listU + (size_t)slot * CAPU);
    const float* table = side ? user_table : item_table;

    uint32_t e0 = (lane < n) ? list[lane] : 0u;
    uint32_t e1 = (lane + 64 < n) ? list[lane + 64] : 0u;
    float acc = 0.f;
    #pragma unroll 4
    for (int j = 0; j < n; ++j) {
        int row = (int)((j < 64) ? __shfl(e0, j) : __shfl(e1, j - 64));
        acc += table[(size_t)row * D + lane];
    }
    if (cnt > caps) {                 // statistically never taken
        int on = *ovfCnt; if (on > OCAP) on = OCAP;
        for (int j = 0; j < on; ++j) {
            uint32_t p = ovf[j];
            if ((int)(p >> 31) == side && (int)((p >> 17) & 0x3FFFu) == slot)
                acc += table[(size_t)(p & 0x1FFFFu) * D + lane];
        }
    }
    float* agg = side ? aggUI : aggIU;
    agg[(size_t)slot * D + lane] = acc;
    if (lane == 0) (side ? degI : degU)[slot] = cnt;
}

// ---------------- per-row GCN transform + feature build ----------------
// 1024 threads = 16 rows/block: amortizes the 32KB Wu/Wi LDS staging.
__global__ __launch_bounds__(1024) void k_build_x(const int* __restrict__ user_id,
                                                  const int* __restrict__ item_id,
                                                  const int* __restrict__ map_u,
                                                  const int* __restrict__ map_i,
                                                  const int* __restrict__ degU,
                                                  const int* __restrict__ degI,
                                                  const float* __restrict__ aggIU,
                                                  const float* __restrict__ aggUI,
                                                  const float* __restrict__ user_table,
                                                  const float* __restrict__ item_table,
                                                  const float* __restrict__ Wu,
                                                  const float* __restrict__ bu,
                                                  const float* __restrict__ Wi,
                                                  const float* __restrict__ bi,
                                                  float* __restrict__ x, int B)
{
    __shared__ float WuL[D * D];
    __shared__ float WiL[D * D];
    for (int t = threadIdx.x; t < D * D; t += blockDim.x) {
        WuL[t] = Wu[t];
        WiL[t] = Wi[t];
    }
    __syncthreads();

    int wid = (blockIdx.x * blockDim.x + threadIdx.x) >> 6;
    int lane = threadIdx.x & 63;
    if (wid >= B) return;

    int u  = user_id[wid];
    int it = item_id[wid];
    int su = map_u[u];
    int si = map_i[it];
    float du = (float)degU[su] + 1.0f;
    float di = (float)degI[si] + 1.0f;
    float gih = aggIU[(size_t)su * D + lane] / du;  // gcn_item_h[lane]
    float guh = aggUI[(size_t)si * D + lane] / di;  // gcn_user_h[lane]

    float accU = bu[lane];
    float accI = bi[lane];
    #pragma unroll 8
    for (int k = 0; k < D; ++k) {
        float gk = __shfl(guh, k);
        accU = fmaf(gk, WuL[k * D + lane], accU);
        float hk = __shfl(gih, k);
        accI = fmaf(hk, WiL[k * D + lane], accI);
    }
    float guo = fmaxf(accU, 0.0f);
    float gio = fmaxf(accI, 0.0f);
    float ue = user_table[(size_t)u * D + lane];
    float ie = item_table[(size_t)it * D + lane];

    size_t xb = (size_t)wid * 256;
    x[xb + lane]       = ue * ie;
    x[xb + 64 + lane]  = ue * gio;
    x[xb + 128 + lane] = guo * ie;
    x[xb + 192 + lane] = guo * gio;
}

// ---------------- layer 1: [B,256]@[256,128] + b1, tanh ----------------
__global__ __launch_bounds__(256) void k_gemm1(const float* __restrict__ x,
                                               const float* __restrict__ W1,
                                               const float* __restrict__ b1,
                                               float* __restrict__ x1, int B)
{
    __shared__ float xs[32][65];
    __shared__ float ws[32][128];
    int tid = threadIdx.x;
    int tx = tid & 31;
    int ty = tid >> 5;
    int row0 = blockIdx.x * 64;
    float acc[8][4] = {};

    for (int k0 = 0; k0 < 256; k0 += 32) {
        {
            int r = tid >> 2;
            int kk = (tid & 3) * 8;
            const float4* src = (const float4*)&x[(size_t)(row0 + r) * 256 + k0 + kk];
            float4 v0 = src[0], v1 = src[1];
            xs[kk + 0][r] = v0.x; xs[kk + 1][r] = v0.y; xs[kk + 2][r] = v0.z; xs[kk + 3][r] = v0.w;
            xs[kk + 4][r] = v1.x; xs[kk + 5][r] = v1.y; xs[kk + 6][r] = v1.z; xs[kk + 7][r] = v1.w;
        }
        {
            const float4* src = (const float4*)(W1 + (size_t)k0 * 128);
            float4* dst = (float4*)&ws[0][0];
            #pragma unroll
            for (int q = 0; q < 4; ++q) dst[tid + q * 256] = src[tid + q * 256];
        }
        __syncthreads();
        #pragma unroll
        for (int k = 0; k < 32; ++k) {
            float a[8], b[4];
            #pragma unroll
            for (int r = 0; r < 8; ++r) a[r] = xs[k][ty * 8 + r];
            #pragma unroll
            for (int c = 0; c < 4; ++c) b[c] = ws[k][tx + 32 * c];
            #pragma unroll
            for (int r = 0; r < 8; ++r)
                #pragma unroll
                for (int c = 0; c < 4; ++c)
                    acc[r][c] = fmaf(a[r], b[c], acc[r][c]);
        }
        __syncthreads();
    }
    #pragma unroll
    for (int r = 0; r < 8; ++r) {
        int row = row0 + ty * 8 + r;
        #pragma unroll
        for (int c = 0; c < 4; ++c) {
            int col = tx + 32 * c;
            x1[(size_t)row * 128 + col] = tanhf(acc[r][c] + b1[col]);
        }
    }
}

// ---------------- layer 2: [B,128]@[128,64] + b2, tanh ----------------
__global__ __launch_bounds__(256) void k_gemm2(const float* __restrict__ x1,
                                               const float* __restrict__ W2,
                                               const float* __restrict__ b2,
                                               float* __restrict__ x2, int B)
{
    __shared__ float xs[32][65];
    __shared__ float ws[32][64];
    int tid = threadIdx.x;
    int tx = tid & 15;
    int ty = tid >> 4;
    int row0 = blockIdx.x * 64;
    float acc[4][4] = {};

    for (int k0 = 0; k0 < 128; k0 += 32) {
        {
            int r = tid >> 2;
            int kk = (tid & 3) * 8;
            const float4* src = (const float4*)&x1[(size_t)(row0 + r) * 128 + k0 + kk];
            float4 v0 = src[0], v1 = src[1];
            xs[kk + 0][r] = v0.x; xs[kk + 1][r] = v0.y; xs[kk + 2][r] = v0.z; xs[kk + 3][r] = v0.w;
            xs[kk + 4][r] = v1.x; xs[kk + 5][r] = v1.y; xs[kk + 6][r] = v1.z; xs[kk + 7][r] = v1.w;
        }
        {
            const float4* src = (const float4*)(W2 + (size_t)k0 * 64);
            float4* dst = (float4*)&ws[0][0];
            #pragma unroll
            for (int q = 0; q < 2; ++q) dst[tid + q * 256] = src[tid + q * 256];
        }
        __syncthreads();
        #pragma unroll
        for (int k = 0; k < 32; ++k) {
            float a[4], b[4];
            #pragma unroll
            for (int r = 0; r < 4; ++r) a[r] = xs[k][ty * 4 + r];
            #pragma unroll
            for (int c = 0; c < 4; ++c) b[c] = ws[k][tx + 16 * c];
            #pragma unroll
            for (int r = 0; r < 4; ++r)
                #pragma unroll
                for (int c = 0; c < 4; ++c)
                    acc[r][c] = fmaf(a[r], b[c], acc[r][c]);
        }
        __syncthreads();
    }
    #pragma unroll
    for (int r = 0; r < 4; ++r) {
        int row = row0 + ty * 4 + r;
        #pragma unroll
        for (int c = 0; c < 4; ++c) {
            int col = tx + 16 * c;
            x2[(size_t)row * 64 + col] = tanhf(acc[r][c] + b2[col]);
        }
    }
}

// ---------------- final: dot with W3 + biases ----------------
__global__ __launch_bounds__(256) void k_final(const float* __restrict__ x2,
                                               const float* __restrict__ W3,
                                               const float* __restrict__ b3,
                                               const float* __restrict__ user_bias,
                                               const float* __restrict__ item_bias,
                                               const int* __restrict__ user_id,
                                               const int* __restrict__ item_id,
                                               float* __restrict__ out, int B)
{
    int wid = (blockIdx.x * blockDim.x + threadIdx.x) >> 6;
    int lane = threadIdx.x & 63;
    if (wid >= B) return;
    float v = x2[(size_t)wid * 64 + lane] * W3[lane];
    #pragma unroll
    for (int off = 32; off; off >>= 1) v += __shfl_xor(v, off);
    if (lane == 0)
        out[wid] = v + b3[0] + user_bias[user_id[wid]] + item_bias[item_id[wid]];
}

extern "C" void kernel_launch(void* const* d_in, const int* in_sizes, int n_in,
                              void* d_out, int out_size, void* d_ws, size_t ws_size,
                              hipStream_t stream)
{
    const float* user_table = (const float*)d_in[0];
    const float* item_table = (const float*)d_in[1];
    const float* Wu = (const float*)d_in[2];
    const float* bu = (const float*)d_in[3];
    const float* Wi = (const float*)d_in[4];
    const float* bi = (const float*)d_in[5];
    const float* W1 = (const float*)d_in[6];
    const float* b1 = (const float*)d_in[7];
    const float* W2 = (const float*)d_in[8];
    const float* b2 = (const float*)d_in[9];
    const float* W3 = (const float*)d_in[10];
    const float* b3 = (const float*)d_in[11];
    const float* user_bias = (const float*)d_in[12];
    const float* item_bias = (const float*)d_in[13];
    const int* user_id = (const int*)d_in[14];
    const int* item_id = (const int*)d_in[15];
    const int* edge_user = (const int*)d_in[16];
    const int* edge_item = (const int*)d_in[17];

    const int N_USER = in_sizes[0] / D;
    const int N_ITEM = in_sizes[1] / D;
    const int B = in_sizes[14];
    const int E = in_sizes[16];

    // ---- workspace layout (bytes) ----
    char* ws = (char*)d_ws;
    const size_t aggIU_off = 0;
    const size_t aggUI_off = aggIU_off + (size_t)B * D * 4;        // 4 MB each
    const size_t degU_off  = aggUI_off + (size_t)B * D * 4;
    const size_t degI_off  = degU_off + (size_t)B * 4;
    const size_t mapu_off  = degI_off + (size_t)B * 4;
    const size_t mapi_off  = mapu_off + (size_t)N_USER * 4;
    size_t x_off = mapi_off + (size_t)N_ITEM * 4;
    x_off = (x_off + 255) & ~(size_t)255;
    const size_t x1_off = x_off + (size_t)B * 256 * 4;             // x: 16.8 MB
    const size_t x2_off = x1_off + (size_t)B * 128 * 4;            // x1: 8.4 MB

    float* aggIU = (float*)(ws + aggIU_off);
    float* aggUI = (float*)(ws + aggUI_off);
    int*   degU  = (int*)(ws + degU_off);
    int*   degI  = (int*)(ws + degI_off);
    int*   map_u = (int*)(ws + mapu_off);
    int*   map_i = (int*)(ws + mapi_off);
    float* x  = (float*)(ws + x_off);
    float* x1 = (float*)(ws + x1_off);
    float* x2 = (float*)(ws + x2_off);

    // CSR lists overlay x (dead before k_build_x writes x):
    uint32_t* listU = (uint32_t*)(ws + x_off);                     // 16384*96*4  = 6.3 MB
    uint32_t* listI = listU + (size_t)B * CAPU;                    // 16384*128*4 = 8.4 MB
    // padded counters + overflow overlay x1 (dead before k_gemm1 writes x1):
    int* cntU = (int*)(ws + x1_off);                               // 16384*64B = 1 MB
    int* cntI = cntU + (size_t)B * 16;                             // 1 MB
    int* ovfCnt = cntI + (size_t)B * 16;
    uint32_t* ovf = (uint32_t*)(ovfCnt + 64);

    hipMemsetAsync(ws + mapu_off, 0xFF, (size_t)(N_USER + N_ITEM) * 4, stream); // maps = -1
    hipMemsetAsync(cntU, 0, (size_t)B * 16 * 4 * 2 + 256 + OCAP * 4, stream);   // counters+ovf

    k_build_maps<<<(B + 255) / 256, 256, 0, stream>>>(user_id, item_id, map_u, map_i, B);

    k_scatter<<<(E + 255) / 256, 256, 0, stream>>>(edge_user, edge_item, map_u, map_i,
                                                   cntU, cntI, listU, listI, ovfCnt, ovf, E);

    k_gather<<<(2 * B) / 4, 256, 0, stream>>>(listU, listI, cntU, cntI,
                                              user_table, item_table, ovfCnt, ovf,
                                              aggIU, aggUI, degU, degI, B);

    k_build_x<<<B / 16, 1024, 0, stream>>>(user_id, item_id, map_u, map_i, degU, degI,
                                           aggIU, aggUI, user_table, item_table,
                                           Wu, bu, Wi, bi, x, B);

    k_gemm1<<<B / 64, 256, 0, stream>>>(x, W1, b1, x1, B);
    k_gemm2<<<B / 64, 256, 0, stream>>>(x1, W2, b2, x2, B);

    k_final<<<B / 4, 256, 0, stream>>>(x2, W3, b3, user_bias, item_bias,
                                       user_id, item_id, (float*)d_out, B);
}

// Round 4
// 272.682 us; speedup vs baseline: 3.0240x; 1.1462x over previous
//
#include <hip/hip_runtime.h>
#include <cstdint>
#include <cstddef>

#define D 64
#define CAPU 96
#define CAPI 128
#define OCAP 4096

// ---------------- build compact slot maps ----------------
__global__ __launch_bounds__(256) void k_build_maps(const int* __restrict__ user_id,
                                                    const int* __restrict__ item_id,
                                                    int* __restrict__ map_u,
                                                    int* __restrict__ map_i, int B)
{
    int i = blockIdx.x * blockDim.x + threadIdx.x;
    if (i < B) {
        atomicCAS(&map_u[user_id[i]], -1, i);
        atomicCAS(&map_i[item_id[i]], -1, i);
    }
}

// ---------------- scatter hit edges into per-slot CSR lists ----------------
// counters padded to 64B (16 ints); 4 edges per thread via int4 loads.
__global__ __launch_bounds__(256) void k_scatter(const int* __restrict__ edge_user,
                                                 const int* __restrict__ edge_item,
                                                 const int* __restrict__ map_u,
                                                 const int* __restrict__ map_i,
                                                 int* __restrict__ cntU,
                                                 int* __restrict__ cntI,
                                                 uint32_t* __restrict__ listU,
                                                 uint32_t* __restrict__ listI,
                                                 int* __restrict__ ovfCnt,
                                                 uint32_t* __restrict__ ovf, int E)
{
    int t = blockIdx.x * blockDim.x + threadIdx.x;
    int base = t * 4;
    if (base >= E) return;

    int us[4], is[4];
    int cnt4 = 4;
    if (base + 3 < E) {
        int4 eu = *(const int4*)(edge_user + base);
        int4 ei = *(const int4*)(edge_item + base);
        us[0] = eu.x; us[1] = eu.y; us[2] = eu.z; us[3] = eu.w;
        is[0] = ei.x; is[1] = ei.y; is[2] = ei.z; is[3] = ei.w;
    } else {
        cnt4 = E - base;
        for (int q = 0; q < cnt4; ++q) { us[q] = edge_user[base + q]; is[q] = edge_item[base + q]; }
    }

    #pragma unroll
    for (int q = 0; q < 4; ++q) {
        if (q >= cnt4) break;
        int u = us[q], it = is[q];
        int su = map_u[u];
        int si = map_i[it];
        if (su >= 0) {
            int pos = atomicAdd(&cntU[su * 16], 1);
            if (pos < CAPU) listU[(size_t)su * CAPU + pos] = (uint32_t)it;
            else { int o = atomicAdd(ovfCnt, 1);
                   if (o < OCAP) ovf[o] = ((uint32_t)su << 17) | (uint32_t)it; }
        }
        if (si >= 0) {
            int pos = atomicAdd(&cntI[si * 16], 1);
            if (pos < CAPI) listI[(size_t)si * CAPI + pos] = (uint32_t)u;
            else { int o = atomicAdd(ovfCnt, 1);
                   if (o < OCAP) ovf[o] = 0x80000000u | ((uint32_t)si << 17) | (uint32_t)u; }
        }
    }
}

// ---------------- gather-reduce: one 16-lane group per (side, slot) ----------------
// 4 independent slots per wave; row loads are float4/lane (256B coalesced per group);
// list reads are same-address broadcasts. Unrolled 2-wide -> 4 rows in flight/group.
__global__ __launch_bounds__(256) void k_gather(const uint32_t* __restrict__ listU,
                                                const uint32_t* __restrict__ listI,
                                                const int* __restrict__ cntU,
                                                const int* __restrict__ cntI,
                                                const float* __restrict__ user_table,
                                                const float* __restrict__ item_table,
                                                const int* __restrict__ ovfCnt,
                                                const uint32_t* __restrict__ ovf,
                                                float* __restrict__ aggIU,
                                                float* __restrict__ aggUI,
                                                int* __restrict__ degU,
                                                int* __restrict__ degI, int B)
{
    int gg = (blockIdx.x * blockDim.x + threadIdx.x) >> 4;  // global 16-lane-group id
    if (gg >= 2 * B) return;
    int l16 = threadIdx.x & 15;
    int side = gg >= B;
    int slot = side ? gg - B : gg;

    int cnt = side ? cntI[slot * 16] : cntU[slot * 16];
    int caps = side ? CAPI : CAPU;
    int n = cnt < caps ? cnt : caps;
    const uint32_t* list = side ? (listI + (size_t)slot * CAPI)
                                : (listU + (size_t)slot * CAPU);
    const float4* table4 = (const float4*)(side ? user_table : item_table);

    float4 a0 = {0.f, 0.f, 0.f, 0.f};
    float4 a1 = {0.f, 0.f, 0.f, 0.f};
    int j = 0;
    #pragma unroll 2
    for (; j + 2 <= n; j += 2) {
        int r0 = (int)list[j];
        int r1 = (int)list[j + 1];
        float4 v0 = table4[(size_t)r0 * 16 + l16];
        float4 v1 = table4[(size_t)r1 * 16 + l16];
        a0.x += v0.x; a0.y += v0.y; a0.z += v0.z; a0.w += v0.w;
        a1.x += v1.x; a1.y += v1.y; a1.z += v1.z; a1.w += v1.w;
    }
    if (j < n) {
        int r0 = (int)list[j];
        float4 v0 = table4[(size_t)r0 * 16 + l16];
        a0.x += v0.x; a0.y += v0.y; a0.z += v0.z; a0.w += v0.w;
    }
    if (cnt > caps) {                 // statistically never taken
        int on = *ovfCnt; if (on > OCAP) on = OCAP;
        for (int k = 0; k < on; ++k) {
            uint32_t p = ovf[k];
            if ((int)(p >> 31) == side && (int)((p >> 17) & 0x3FFFu) == slot) {
                float4 v = table4[(size_t)(p & 0x1FFFFu) * 16 + l16];
                a0.x += v.x; a0.y += v.y; a0.z += v.z; a0.w += v.w;
            }
        }
    }
    float4 acc = {a0.x + a1.x, a0.y + a1.y, a0.z + a1.z, a0.w + a1.w};
    float4* agg4 = (float4*)(side ? aggUI : aggIU);
    agg4[(size_t)slot * 16 + l16] = acc;
    if (l16 == 0) (side ? degI : degU)[slot] = cnt;
}

// ---------------- per-row GCN transform + feature build ----------------
__global__ __launch_bounds__(1024) void k_build_x(const int* __restrict__ user_id,
                                                  const int* __restrict__ item_id,
                                                  const int* __restrict__ map_u,
                                                  const int* __restrict__ map_i,
                                                  const int* __restrict__ degU,
                                                  const int* __restrict__ degI,
                                                  const float* __restrict__ aggIU,
                                                  const float* __restrict__ aggUI,
                                                  const float* __restrict__ user_table,
                                                  const float* __restrict__ item_table,
                                                  const float* __restrict__ Wu,
                                                  const float* __restrict__ bu,
                                                  const float* __restrict__ Wi,
                                                  const float* __restrict__ bi,
                                                  float* __restrict__ x, int B)
{
    __shared__ float WuL[D * D];
    __shared__ float WiL[D * D];
    for (int t = threadIdx.x; t < D * D; t += blockDim.x) {
        WuL[t] = Wu[t];
        WiL[t] = Wi[t];
    }
    __syncthreads();

    int wid = (blockIdx.x * blockDim.x + threadIdx.x) >> 6;
    int lane = threadIdx.x & 63;
    if (wid >= B) return;

    int u  = user_id[wid];
    int it = item_id[wid];
    int su = map_u[u];
    int si = map_i[it];
    float du = (float)degU[su] + 1.0f;
    float di = (float)degI[si] + 1.0f;
    float gih = aggIU[(size_t)su * D + lane] / du;  // gcn_item_h[lane]
    float guh = aggUI[(size_t)si * D + lane] / di;  // gcn_user_h[lane]

    float accU = bu[lane];
    float accI = bi[lane];
    #pragma unroll 8
    for (int k = 0; k < D; ++k) {
        float gk = __shfl(guh, k);
        accU = fmaf(gk, WuL[k * D + lane], accU);
        float hk = __shfl(gih, k);
        accI = fmaf(hk, WiL[k * D + lane], accI);
    }
    float guo = fmaxf(accU, 0.0f);
    float gio = fmaxf(accI, 0.0f);
    float ue = user_table[(size_t)u * D + lane];
    float ie = item_table[(size_t)it * D + lane];

    size_t xb = (size_t)wid * 256;
    x[xb + lane]       = ue * ie;
    x[xb + 64 + lane]  = ue * gio;
    x[xb + 128 + lane] = guo * ie;
    x[xb + 192 + lane] = guo * gio;
}

// ---------------- layer 1: [B,256]@[256,128] + b1, tanh ----------------
__global__ __launch_bounds__(256) void k_gemm1(const float* __restrict__ x,
                                               const float* __restrict__ W1,
                                               const float* __restrict__ b1,
                                               float* __restrict__ x1, int B)
{
    __shared__ float xs[32][65];
    __shared__ float ws[32][128];
    int tid = threadIdx.x;
    int tx = tid & 31;
    int ty = tid >> 5;
    int row0 = blockIdx.x * 64;
    float acc[8][4] = {};

    for (int k0 = 0; k0 < 256; k0 += 32) {
        {
            int r = tid >> 2;
            int kk = (tid & 3) * 8;
            const float4* src = (const float4*)&x[(size_t)(row0 + r) * 256 + k0 + kk];
            float4 v0 = src[0], v1 = src[1];
            xs[kk + 0][r] = v0.x; xs[kk + 1][r] = v0.y; xs[kk + 2][r] = v0.z; xs[kk + 3][r] = v0.w;
            xs[kk + 4][r] = v1.x; xs[kk + 5][r] = v1.y; xs[kk + 6][r] = v1.z; xs[kk + 7][r] = v1.w;
        }
        {
            const float4* src = (const float4*)(W1 + (size_t)k0 * 128);
            float4* dst = (float4*)&ws[0][0];
            #pragma unroll
            for (int q = 0; q < 4; ++q) dst[tid + q * 256] = src[tid + q * 256];
        }
        __syncthreads();
        #pragma unroll
        for (int k = 0; k < 32; ++k) {
            float a[8], b[4];
            #pragma unroll
            for (int r = 0; r < 8; ++r) a[r] = xs[k][ty * 8 + r];
            #pragma unroll
            for (int c = 0; c < 4; ++c) b[c] = ws[k][tx + 32 * c];
            #pragma unroll
            for (int r = 0; r < 8; ++r)
                #pragma unroll
                for (int c = 0; c < 4; ++c)
                    acc[r][c] = fmaf(a[r], b[c], acc[r][c]);
        }
        __syncthreads();
    }
    #pragma unroll
    for (int r = 0; r < 8; ++r) {
        int row = row0 + ty * 8 + r;
        #pragma unroll
        for (int c = 0; c < 4; ++c) {
            int col = tx + 32 * c;
            x1[(size_t)row * 128 + col] = tanhf(acc[r][c] + b1[col]);
        }
    }
}

// ---------------- layer 2 + head: tanh(x1@W2+b2) @ W3 + b3 + biases ----------------
__global__ __launch_bounds__(256) void k_gemm2f(const float* __restrict__ x1,
                                                const float* __restrict__ W2,
                                                const float* __restrict__ b2,
                                                const float* __restrict__ W3,
                                                const float* __restrict__ b3,
                                                const float* __restrict__ user_bias,
                                                const float* __restrict__ item_bias,
                                                const int* __restrict__ user_id,
                                                const int* __restrict__ item_id,
                                                float* __restrict__ out, int B)
{
    __shared__ float xs[32][65];
    __shared__ float ws[32][64];
    int tid = threadIdx.x;
    int tx = tid & 15;      // cols tx + 16*c
    int ty = tid >> 4;      // rows ty*4 + r
    int row0 = blockIdx.x * 64;
    float acc[4][4] = {};

    for (int k0 = 0; k0 < 128; k0 += 32) {
        {
            int r = tid >> 2;
            int kk = (tid & 3) * 8;
            const float4* src = (const float4*)&x1[(size_t)(row0 + r) * 128 + k0 + kk];
            float4 v0 = src[0], v1 = src[1];
            xs[kk + 0][r] = v0.x; xs[kk + 1][r] = v0.y; xs[kk + 2][r] = v0.z; xs[kk + 3][r] = v0.w;
            xs[kk + 4][r] = v1.x; xs[kk + 5][r] = v1.y; xs[kk + 6][r] = v1.z; xs[kk + 7][r] = v1.w;
        }
        {
            const float4* src = (const float4*)(W2 + (size_t)k0 * 64);
            float4* dst = (float4*)&ws[0][0];
            #pragma unroll
            for (int q = 0; q < 2; ++q) dst[tid + q * 256] = src[tid + q * 256];
        }
        __syncthreads();
        #pragma unroll
        for (int k = 0; k < 32; ++k) {
            float a[4], b[4];
            #pragma unroll
            for (int r = 0; r < 4; ++r) a[r] = xs[k][ty * 4 + r];
            #pragma unroll
            for (int c = 0; c < 4; ++c) b[c] = ws[k][tx + 16 * c];
            #pragma unroll
            for (int r = 0; r < 4; ++r)
                #pragma unroll
                for (int c = 0; c < 4; ++c)
                    acc[r][c] = fmaf(a[r], b[c], acc[r][c]);
        }
        __syncthreads();
    }

    float w3v[4], b2v[4];
    #pragma unroll
    for (int c = 0; c < 4; ++c) {
        int col = tx + 16 * c;
        w3v[c] = W3[col];
        b2v[c] = b2[col];
    }
    #pragma unroll
    for (int r = 0; r < 4; ++r) {
        float p = 0.f;
        #pragma unroll
        for (int c = 0; c < 4; ++c)
            p += tanhf(acc[r][c] + b2v[c]) * w3v[c];
        p += __shfl_xor(p, 1);
        p += __shfl_xor(p, 2);
        p += __shfl_xor(p, 4);
        p += __shfl_xor(p, 8);
        if (tx == 0) {
            int row = row0 + ty * 4 + r;
            out[row] = p + b3[0] + user_bias[user_id[row]] + item_bias[item_id[row]];
        }
    }
}

extern "C" void kernel_launch(void* const* d_in, const int* in_sizes, int n_in,
                              void* d_out, int out_size, void* d_ws, size_t ws_size,
                              hipStream_t stream)
{
    const float* user_table = (const float*)d_in[0];
    const float* item_table = (const float*)d_in[1];
    const float* Wu = (const float*)d_in[2];
    const float* bu = (const float*)d_in[3];
    const float* Wi = (const float*)d_in[4];
    const float* bi = (const float*)d_in[5];
    const float* W1 = (const float*)d_in[6];
    const float* b1 = (const float*)d_in[7];
    const float* W2 = (const float*)d_in[8];
    const float* b2 = (const float*)d_in[9];
    const float* W3 = (const float*)d_in[10];
    const float* b3 = (const float*)d_in[11];
    const float* user_bias = (const float*)d_in[12];
    const float* item_bias = (const float*)d_in[13];
    const int* user_id = (const int*)d_in[14];
    const int* item_id = (const int*)d_in[15];
    const int* edge_user = (const int*)d_in[16];
    const int* edge_item = (const int*)d_in[17];

    const int N_USER = in_sizes[0] / D;
    const int N_ITEM = in_sizes[1] / D;
    const int B = in_sizes[14];
    const int E = in_sizes[16];

    // ---- workspace layout (bytes) ----
    char* ws = (char*)d_ws;
    const size_t aggIU_off = 0;
    const size_t aggUI_off = aggIU_off + (size_t)B * D * 4;        // 4 MB each
    const size_t degU_off  = aggUI_off + (size_t)B * D * 4;
    const size_t degI_off  = degU_off + (size_t)B * 4;
    const size_t mapu_off  = degI_off + (size_t)B * 4;
    const size_t mapi_off  = mapu_off + (size_t)N_USER * 4;
    size_t x_off = mapi_off + (size_t)N_ITEM * 4;
    x_off = (x_off + 255) & ~(size_t)255;
    const size_t x1_off = x_off + (size_t)B * 256 * 4;             // x: 16.8 MB

    float* aggIU = (float*)(ws + aggIU_off);
    float* aggUI = (float*)(ws + aggUI_off);
    int*   degU  = (int*)(ws + degU_off);
    int*   degI  = (int*)(ws + degI_off);
    int*   map_u = (int*)(ws + mapu_off);
    int*   map_i = (int*)(ws + mapi_off);
    float* x  = (float*)(ws + x_off);
    float* x1 = (float*)(ws + x1_off);

    // CSR lists overlay x (dead before k_build_x writes x):
    uint32_t* listU = (uint32_t*)(ws + x_off);                     // 16384*96*4  = 6.3 MB
    uint32_t* listI = listU + (size_t)B * CAPU;                    // 16384*128*4 = 8.4 MB
    // padded counters + overflow overlay x1 (dead before k_gemm1 writes x1):
    int* cntU = (int*)(ws + x1_off);                               // 1 MB
    int* cntI = cntU + (size_t)B * 16;                             // 1 MB
    int* ovfCnt = cntI + (size_t)B * 16;
    uint32_t* ovf = (uint32_t*)(ovfCnt + 64);

    hipMemsetAsync(ws + mapu_off, 0xFF, (size_t)(N_USER + N_ITEM) * 4, stream); // maps = -1
    hipMemsetAsync(cntU, 0, (size_t)B * 16 * 4 * 2 + 256 + OCAP * 4, stream);   // counters+ovf

    k_build_maps<<<(B + 255) / 256, 256, 0, stream>>>(user_id, item_id, map_u, map_i, B);

    k_scatter<<<(E / 4 + 255) / 256, 256, 0, stream>>>(edge_user, edge_item, map_u, map_i,
                                                       cntU, cntI, listU, listI, ovfCnt, ovf, E);

    k_gather<<<(2 * B) / 16, 256, 0, stream>>>(listU, listI, cntU, cntI,
                                               user_table, item_table, ovfCnt, ovf,
                                               aggIU, aggUI, degU, degI, B);

    k_build_x<<<B / 16, 1024, 0, stream>>>(user_id, item_id, map_u, map_i, degU, degI,
                                           aggIU, aggUI, user_table, item_table,
                                           Wu, bu, Wi, bi, x, B);

    k_gemm1<<<B / 64, 256, 0, stream>>>(x, W1, b1, x1, B);

    k_gemm2f<<<B / 64, 256, 0, stream>>>(x1, W2, b2, W3, b3, user_bias, item_bias,
                                         user_id, item_id, (float*)d_out, B);
}

// Round 6
// 242.712 us; speedup vs baseline: 3.3974x; 1.1235x over previous
//
#include <hip/hip_runtime.h>
#include <cstdint>
#include <cstddef>

#define D 64
#define CAPU 96
#define CAPI 128
#define OCAP 4096
#define GR 32   // rows per block in k_gcn / k_mlp

// ---------------- build compact slot maps ----------------
__global__ __launch_bounds__(256) void k_build_maps(const int* __restrict__ user_id,
                                                    const int* __restrict__ item_id,
                                                    int* __restrict__ map_u,
                                                    int* __restrict__ map_i, int B)
{
    int i = blockIdx.x * blockDim.x + threadIdx.x;
    if (i < B) {
        atomicCAS(&map_u[user_id[i]], -1, i);
        atomicCAS(&map_i[item_id[i]], -1, i);
    }
}

// ---------------- scatter hit edges into per-slot CSR lists ----------------
__global__ __launch_bounds__(256) void k_scatter(const int* __restrict__ edge_user,
                                                 const int* __restrict__ edge_item,
                                                 const int* __restrict__ map_u,
                                                 const int* __restrict__ map_i,
                                                 int* __restrict__ cntU,
                                                 int* __restrict__ cntI,
                                                 uint32_t* __restrict__ listU,
                                                 uint32_t* __restrict__ listI,
                                                 int* __restrict__ ovfCnt,
                                                 uint32_t* __restrict__ ovf, int E)
{
    int t = blockIdx.x * blockDim.x + threadIdx.x;
    int base = t * 4;
    if (base >= E) return;

    int us[4], is[4];
    int cnt4 = 4;
    if (base + 3 < E) {
        int4 eu = *(const int4*)(edge_user + base);
        int4 ei = *(const int4*)(edge_item + base);
        us[0] = eu.x; us[1] = eu.y; us[2] = eu.z; us[3] = eu.w;
        is[0] = ei.x; is[1] = ei.y; is[2] = ei.z; is[3] = ei.w;
    } else {
        cnt4 = E - base;
        for (int q = 0; q < cnt4; ++q) { us[q] = edge_user[base + q]; is[q] = edge_item[base + q]; }
    }

    #pragma unroll
    for (int q = 0; q < 4; ++q) {
        if (q >= cnt4) break;
        int u = us[q], it = is[q];
        int su = map_u[u];
        int si = map_i[it];
        if (su >= 0) {
            int pos = atomicAdd(&cntU[su * 16], 1);
            if (pos < CAPU) listU[(size_t)su * CAPU + pos] = (uint32_t)it;
            else { int o = atomicAdd(ovfCnt, 1);
                   if (o < OCAP) ovf[o] = ((uint32_t)su << 17) | (uint32_t)it; }
        }
        if (si >= 0) {
            int pos = atomicAdd(&cntI[si * 16], 1);
            if (pos < CAPI) listI[(size_t)si * CAPI + pos] = (uint32_t)u;
            else { int o = atomicAdd(ovfCnt, 1);
                   if (o < OCAP) ovf[o] = 0x80000000u | ((uint32_t)si << 17) | (uint32_t)u; }
        }
    }
}

// ---------------- gather-reduce + normalize: one 16-lane group per (side,slot) ----------------
__global__ __launch_bounds__(256) void k_gather(const uint32_t* __restrict__ listU,
                                                const uint32_t* __restrict__ listI,
                                                const int* __restrict__ cntU,
                                                const int* __restrict__ cntI,
                                                const float* __restrict__ user_table,
                                                const float* __restrict__ item_table,
                                                const int* __restrict__ ovfCnt,
                                                const uint32_t* __restrict__ ovf,
                                                float* __restrict__ aggIU,
                                                float* __restrict__ aggUI, int B)
{
    int gg = (blockIdx.x * blockDim.x + threadIdx.x) >> 4;
    if (gg >= 2 * B) return;
    int l16 = threadIdx.x & 15;
    int side = gg >= B;
    int slot = side ? gg - B : gg;

    int cnt = side ? cntI[slot * 16] : cntU[slot * 16];
    int caps = side ? CAPI : CAPU;
    int n = cnt < caps ? cnt : caps;
    const uint32_t* list = side ? (listI + (size_t)slot * CAPI)
                                : (listU + (size_t)slot * CAPU);
    const float4* table4 = (const float4*)(side ? user_table : item_table);

    float4 a0 = {0.f, 0.f, 0.f, 0.f};
    float4 a1 = {0.f, 0.f, 0.f, 0.f};
    int j = 0;
    #pragma unroll 2
    for (; j + 2 <= n; j += 2) {
        int r0 = (int)list[j];
        int r1 = (int)list[j + 1];
        float4 v0 = table4[(size_t)r0 * 16 + l16];
        float4 v1 = table4[(size_t)r1 * 16 + l16];
        a0.x += v0.x; a0.y += v0.y; a0.z += v0.z; a0.w += v0.w;
        a1.x += v1.x; a1.y += v1.y; a1.z += v1.z; a1.w += v1.w;
    }
    if (j < n) {
        int r0 = (int)list[j];
        float4 v0 = table4[(size_t)r0 * 16 + l16];
        a0.x += v0.x; a0.y += v0.y; a0.z += v0.z; a0.w += v0.w;
    }
    if (cnt > caps) {                 // statistically never taken
        int on = *ovfCnt; if (on > OCAP) on = OCAP;
        for (int k = 0; k < on; ++k) {
            uint32_t p = ovf[k];
            if ((int)(p >> 31) == side && (int)((p >> 17) & 0x3FFFu) == slot) {
                float4 v = table4[(size_t)(p & 0x1FFFFu) * 16 + l16];
                a0.x += v.x; a0.y += v.y; a0.z += v.z; a0.w += v.w;
            }
        }
    }
    float inv = 1.0f / ((float)cnt + 1.0f);      // deg = cnt + 1 (reference)
    float4 acc = {(a0.x + a1.x) * inv, (a0.y + a1.y) * inv,
                  (a0.z + a1.z) * inv, (a0.w + a1.w) * inv};
    float4* agg4 = (float4*)(side ? aggUI : aggIU);
    agg4[(size_t)slot * 16 + l16] = acc;
}

// ---------------- GCN transforms: Xgi = relu(aggIU_n[su]@Wi+bi), Xgu = relu(aggUI_n[si]@Wu+bu) ----
// 32 rows/block; blocks [0, B/GR): item-transform; [B/GR, 2B/GR): user-transform.
__global__ __launch_bounds__(256) void k_gcn(const int* __restrict__ user_id,
                                             const int* __restrict__ item_id,
                                             const int* __restrict__ map_u,
                                             const int* __restrict__ map_i,
                                             const float* __restrict__ aggIU,
                                             const float* __restrict__ aggUI,
                                             const float* __restrict__ Wi,
                                             const float* __restrict__ bi,
                                             const float* __restrict__ Wu,
                                             const float* __restrict__ bu,
                                             float* __restrict__ Xgi,
                                             float* __restrict__ Xgu, int B)
{
    __shared__ float A[GR][68];      // [row][k], padded (stride 272B, 16B-aligned)
    __shared__ float Wl[64][64];
    __shared__ int sslot[GR];
    int t = threadIdx.x;
    int nb = B / GR;
    int b = blockIdx.x;
    int side = b >= nb;
    int row0 = (side ? b - nb : b) * GR;

    if (t < GR) {
        int r = row0 + t;
        sslot[t] = side ? map_i[item_id[r]] : map_u[user_id[r]];
    }
    {   // stage W (64x64 row-major, [in][out])
        const float4* Wg = (const float4*)(side ? Wu : Wi);
        float4* Wl4 = (float4*)&Wl[0][0];
        #pragma unroll
        for (int q = 0; q < 4; ++q) Wl4[t + q * 256] = Wg[t + q * 256];
    }
    __syncthreads();
    {   // stage A: 32 gathered (normalized) agg rows
        const float4* agg4 = (const float4*)(side ? aggUI : aggIU);
        #pragma unroll
        for (int q = 0; q < 2; ++q) {
            int idx = t * 2 + q;           // 0..511
            int r = idx >> 4, l16 = idx & 15;
            ((float4*)&A[r][0])[l16] = agg4[(size_t)sslot[r] * 16 + l16];
        }
    }
    __syncthreads();

    const float* bias = side ? bu : bi;
    int tx = t & 15, ty = t >> 4;          // cols tx+16c, rows 2*ty+r
    float acc[2][4] = {};
    for (int k = 0; k < 64; ++k) {
        float a0 = A[2 * ty][k];
        float a1 = A[2 * ty + 1][k];
        #pragma unroll
        for (int c = 0; c < 4; ++c) {
            float w = Wl[k][tx + 16 * c];
            acc[0][c] = fmaf(a0, w, acc[0][c]);
            acc[1][c] = fmaf(a1, w, acc[1][c]);
        }
    }
    float* Xg = side ? Xgu : Xgi;
    #pragma unroll
    for (int r = 0; r < 2; ++r) {
        int row = row0 + 2 * ty + r;
        #pragma unroll
        for (int c = 0; c < 4; ++c) {
            int col = tx + 16 * c;
            Xg[(size_t)row * 64 + col] = fmaxf(acc[r][c] + bias[col], 0.f);
        }
    }
}

// ---------------- fused MLP: x1 = tanh(x@W1+b1) built per 64-wide K-slice;
//                  x2 = tanh(x1@W2+b2); out = x2@W3 + b3 + biases ----------------
// x is never materialized: x@W1 = sum_j (Fa_j * Fb_j) @ W1[j*64:(j+1)*64, :]
__global__ __launch_bounds__(256) void k_mlp(const int* __restrict__ user_id,
                                             const int* __restrict__ item_id,
                                             const float* __restrict__ user_table,
                                             const float* __restrict__ item_table,
                                             const float* __restrict__ Xgi,
                                             const float* __restrict__ Xgu,
                                             const float* __restrict__ W1,
                                             const float* __restrict__ b1,
                                             const float* __restrict__ W2,
                                             const float* __restrict__ b2,
                                             const float* __restrict__ W3,
                                             const float* __restrict__ b3,
                                             const float* __restrict__ user_bias,
                                             const float* __restrict__ item_bias,
                                             float* __restrict__ out, int B)
{
    __shared__ float Fbuf[64][68];   // rows 0-31: factor A; rows 32-63: factor B; later x1t[32][132]
    __shared__ float WB[8192];       // W1 slice [64][128], then W2 [128][64]
    __shared__ int sU[GR], sI[GR];
    int t = threadIdx.x;
    int row0 = blockIdx.x * GR;
    if (t < GR) { sU[t] = user_id[row0 + t]; sI[t] = item_id[row0 + t]; }
    __syncthreads();

    int tx1 = t & 31, ty1 = t >> 5;        // cols tx1+32c (128), rows 4*ty1+r (32)
    float acc1[4][4] = {};

    // phase factor kinds: 0=ue(gather), 1=ie(gather), 2=Xgi(contig), 3=Xgu(contig)
    const int fkA[4] = {0, 0, 3, 3};
    const int fkB[4] = {1, 2, 1, 2};
    for (int j = 0; j < 4; ++j) {
        #pragma unroll
        for (int half = 0; half < 2; ++half) {
            int kind = half ? fkB[j] : fkA[j];
            #pragma unroll
            for (int q = 0; q < 2; ++q) {
                int idx = t * 2 + q;       // 0..511
                int r = idx >> 4, l16 = idx & 15;
                const float4* src;
                size_t rowidx;
                if (kind == 0)      { src = (const float4*)user_table; rowidx = (size_t)sU[r]; }
                else if (kind == 1) { src = (const float4*)item_table; rowidx = (size_t)sI[r]; }
                else if (kind == 2) { src = (const float4*)Xgi; rowidx = (size_t)(row0 + r); }
                else                { src = (const float4*)Xgu; rowidx = (size_t)(row0 + r); }
                ((float4*)&Fbuf[half * 32 + r][0])[l16] = src[rowidx * 16 + l16];
            }
        }
        {   // stage W1 slice j (64x128 floats, contiguous)
            const float4* w4 = (const float4*)W1 + (size_t)j * 2048;
            float4* d = (float4*)WB;
            #pragma unroll
            for (int q = 0; q < 8; ++q) d[t + q * 256] = w4[t + q * 256];
        }
        __syncthreads();
        for (int k = 0; k < 64; ++k) {
            float a[4], b[4];
            #pragma unroll
            for (int r = 0; r < 4; ++r)
                a[r] = Fbuf[4 * ty1 + r][k] * Fbuf[32 + 4 * ty1 + r][k];
            #pragma unroll
            for (int c = 0; c < 4; ++c) b[c] = WB[k * 128 + tx1 + 32 * c];
            #pragma unroll
            for (int r = 0; r < 4; ++r)
                #pragma unroll
                for (int c = 0; c < 4; ++c)
                    acc1[r][c] = fmaf(a[r], b[c], acc1[r][c]);
        }
        __syncthreads();
    }

    // x1 tile -> LDS (alias Fbuf as [32][132]); stage W2 into WB
    float* x1t = &Fbuf[0][0];
    #pragma unroll
    for (int r = 0; r < 4; ++r)
        #pragma unroll
        for (int c = 0; c < 4; ++c) {
            int col = tx1 + 32 * c;
            x1t[(4 * ty1 + r) * 132 + col] = tanhf(acc1[r][c] + b1[col]);
        }
    {   // W2: 128x64 floats contiguous
        const float4* w4 = (const float4*)W2;
        float4* d = (float4*)WB;
        #pragma unroll
        for (int q = 0; q < 8; ++q) d[t + q * 256] = w4[t + q * 256];
    }
    __syncthreads();

    int tx2 = t & 15, ty2 = t >> 4;        // cols tx2+16c (64), rows 2*ty2+r (32)
    float acc2[2][4] = {};
    for (int k = 0; k < 128; ++k) {
        float a0 = x1t[(2 * ty2) * 132 + k];
        float a1 = x1t[(2 * ty2 + 1) * 132 + k];
        #pragma unroll
        for (int c = 0; c < 4; ++c) {
            float w = WB[k * 64 + tx2 + 16 * c];
            acc2[0][c] = fmaf(a0, w, acc2[0][c]);
            acc2[1][c] = fmaf(a1, w, acc2[1][c]);
        }
    }
    float b3v = b3[0];
    #pragma unroll
    for (int r = 0; r < 2; ++r) {
        int lr = 2 * ty2 + r;
        float p = 0.f;
        #pragma unroll
        for (int c = 0; c < 4; ++c) {
            int col = tx2 + 16 * c;
            p += tanhf(acc2[r][c] + b2[col]) * W3[col];
        }
        p += __shfl_xor(p, 1);
        p += __shfl_xor(p, 2);
        p += __shfl_xor(p, 4);
        p += __shfl_xor(p, 8);
        if (tx2 == 0)
            out[row0 + lr] = p + b3v + user_bias[sU[lr]] + item_bias[sI[lr]];
    }
}

extern "C" void kernel_launch(void* const* d_in, const int* in_sizes, int n_in,
                              void* d_out, int out_size, void* d_ws, size_t ws_size,
                              hipStream_t stream)
{
    const float* user_table = (const float*)d_in[0];
    const float* item_table = (const float*)d_in[1];
    const float* Wu = (const float*)d_in[2];
    const float* bu = (const float*)d_in[3];
    const float* Wi = (const float*)d_in[4];
    const float* bi = (const float*)d_in[5];
    const float* W1 = (const float*)d_in[6];
    const float* b1 = (const float*)d_in[7];
    const float* W2 = (const float*)d_in[8];
    const float* b2 = (const float*)d_in[9];
    const float* W3 = (const float*)d_in[10];
    const float* b3 = (const float*)d_in[11];
    const float* user_bias = (const float*)d_in[12];
    const float* item_bias = (const float*)d_in[13];
    const int* user_id = (const int*)d_in[14];
    const int* item_id = (const int*)d_in[15];
    const int* edge_user = (const int*)d_in[16];
    const int* edge_item = (const int*)d_in[17];

    const int N_USER = in_sizes[0] / D;
    const int N_ITEM = in_sizes[1] / D;
    const int B = in_sizes[14];
    const int E = in_sizes[16];

    // ---- workspace layout (bytes); all sub-sizes are multiples of 16 ----
    char* ws = (char*)d_ws;
    size_t off = 0;
    const size_t aggIU_off = off; off += (size_t)B * D * 4;        // 4.19 MB
    const size_t aggUI_off = off; off += (size_t)B * D * 4;        // 4.19 MB
    const size_t mapu_off  = off; off += (size_t)N_USER * 4;       // 400 KB
    const size_t mapi_off  = off; off += (size_t)N_ITEM * 4;       // 200 KB
    const size_t cntU_off  = off; off += (size_t)B * 16 * 4;       // 1.05 MB (64B-padded)
    const size_t cntI_off  = off; off += (size_t)B * 16 * 4;       // 1.05 MB
    const size_t ovfc_off  = off; off += 256;
    const size_t ovf_off   = off; off += (size_t)OCAP * 4;
    const size_t listU_off = off; off += (size_t)B * CAPU * 4;     // 6.29 MB
    const size_t listI_off = off; off += (size_t)B * CAPI * 4;     // 8.39 MB

    float* aggIU = (float*)(ws + aggIU_off);
    float* aggUI = (float*)(ws + aggUI_off);
    int*   map_u = (int*)(ws + mapu_off);
    int*   map_i = (int*)(ws + mapi_off);
    int*   cntU  = (int*)(ws + cntU_off);
    int*   cntI  = (int*)(ws + cntI_off);
    int*   ovfCnt = (int*)(ws + ovfc_off);
    uint32_t* ovf = (uint32_t*)(ws + ovf_off);
    uint32_t* listU = (uint32_t*)(ws + listU_off);
    uint32_t* listI = (uint32_t*)(ws + listI_off);
    // Xgi/Xgu overlay the CSR lists (lists dead after k_gather)
    float* Xgi = (float*)(ws + listU_off);
    float* Xgu = Xgi + (size_t)B * D;

    hipMemsetAsync(ws + mapu_off, 0xFF, (size_t)(N_USER + N_ITEM) * 4, stream);         // maps = -1
    hipMemsetAsync(ws + cntU_off, 0, (size_t)B * 16 * 4 * 2 + 256 + OCAP * 4, stream);  // cnt+ovf = 0

    k_build_maps<<<(B + 255) / 256, 256, 0, stream>>>(user_id, item_id, map_u, map_i, B);

    k_scatter<<<(E / 4 + 255) / 256, 256, 0, stream>>>(edge_user, edge_item, map_u, map_i,
                                                       cntU, cntI, listU, listI, ovfCnt, ovf, E);

    k_gather<<<(2 * B) / 16, 256, 0, stream>>>(listU, listI, cntU, cntI,
                                               user_table, item_table, ovfCnt, ovf,
                                               aggIU, aggUI, B);

    k_gcn<<<2 * (B / GR), 256, 0, stream>>>(user_id, item_id, map_u, map_i,
                                            aggIU, aggUI, Wi, bi, Wu, bu, Xgi, Xgu, B);

    k_mlp<<<B / GR, 256, 0, stream>>>(user_id, item_id, user_table, item_table,
                                      Xgi, Xgu, W1, b1, W2, b2, W3, b3,
                                      user_bias, item_bias, (float*)d_out, B);
}